// Round 11
// baseline (887.155 us; speedup 1.0000x reference)
//
#include <hip/hip_runtime.h>
#include <hip/hip_bf16.h>

#define N_NODES 50000
#define E_EDGES 800000
#define ETOT (E_EDGES + N_NODES)
#define HC 256
#define NHEAD 4
#define CHAN 64
#define NEG 0.2f
#define NBLK ((N_NODES + 1023) / 1024)   // 49

typedef _Float16 half8 __attribute__((ext_vector_type(8)));
typedef _Float16 half4v __attribute__((ext_vector_type(4)));
typedef float float4v __attribute__((ext_vector_type(4)));

// ---------------- CSR build (once per call; shared across all 5 layers) ----------------
// ONE atomic pass: count_rank persists the atomicAdd return value as the edge's
// rank within its dst segment; fill is a deterministic (atomic-free) scatter.

__global__ __launch_bounds__(256) void count_rank_kernel(const int* __restrict__ ei,
                                                         int* __restrict__ counts,
                                                         int* __restrict__ rank) {
    int base = blockIdx.x * 1024 + threadIdx.x;
    int dst[4];
    bool val[4];
    #pragma unroll
    for (int r = 0; r < 4; ++r) {
        int i = base + r * 256;
        val[r] = (i < ETOT);
        dst[r] = 0;
        if (val[r]) dst[r] = (i < E_EDGES) ? ei[E_EDGES + i] : (i - E_EDGES);
    }
    int rk[4];
    #pragma unroll
    for (int r = 0; r < 4; ++r)
        if (val[r]) rk[r] = atomicAdd(&counts[dst[r]], 1);
    #pragma unroll
    for (int r = 0; r < 4; ++r)
        if (val[r]) rank[base + r * 256] = rk[r];
}

__global__ __launch_bounds__(256) void blocksum_kernel(const int* __restrict__ counts,
                                                       int* __restrict__ blocksums) {
    __shared__ int s[4];
    int b = blockIdx.x, tid = threadIdx.x;
    int base = b * 1024;
    int sum = 0;
    #pragma unroll
    for (int r = 0; r < 4; ++r) {
        int idx = base + r * 256 + tid;
        sum += (idx < N_NODES) ? counts[idx] : 0;
    }
    #pragma unroll
    for (int m = 1; m < 64; m <<= 1) sum += __shfl_xor(sum, m, 64);
    if ((tid & 63) == 0) s[tid >> 6] = sum;
    __syncthreads();
    if (tid == 0) blocksums[b] = s[0] + s[1] + s[2] + s[3];
}

__global__ __launch_bounds__(64) void blockscan_kernel(int* __restrict__ blocksums) {
    int tid = threadIdx.x;
    int v = (tid < NBLK) ? blocksums[tid] : 0;
    #pragma unroll
    for (int off = 1; off < 64; off <<= 1) {
        int t = __shfl_up(v, off, 64);
        if (tid >= off) v += t;
    }
    if (tid < NBLK) blocksums[tid] = v;   // inclusive
}

__global__ __launch_bounds__(1024) void scatter_scan_kernel(const int* __restrict__ counts,
                                                            const int* __restrict__ blocksums,
                                                            int* __restrict__ offsets) {
    __shared__ int s[1024];
    int b = blockIdx.x, tid = threadIdx.x;
    int idx = b * 1024 + tid;
    int v = (idx < N_NODES) ? counts[idx] : 0;
    s[tid] = v;
    __syncthreads();
    for (int off = 1; off < 1024; off <<= 1) {
        int t = (tid >= off) ? s[tid - off] : 0;
        __syncthreads();
        s[tid] += t;
        __syncthreads();
    }
    int excl = s[tid] - v + (b > 0 ? blocksums[b - 1] : 0);
    if (idx < N_NODES) offsets[idx] = excl;
    if (idx == N_NODES - 1) offsets[N_NODES] = excl + v;
}

// atomic-free scatter: pos = offsets[dst] + rank (unique by construction).
__global__ __launch_bounds__(256) void fill_kernel(const int* __restrict__ ei,
                                                   const int* __restrict__ rank,
                                                   const int* __restrict__ offsets,
                                                   int2* __restrict__ csr) {
    int base = blockIdx.x * 1024 + threadIdx.x;
    #pragma unroll
    for (int r = 0; r < 4; ++r) {
        int i = base + r * 256;
        if (i >= ETOT) continue;
        int src, dst;
        if (i < E_EDGES) { src = ei[i]; dst = ei[E_EDGES + i]; }
        else             { src = i - E_EDGES; dst = src; }
        int pos = offsets[dst] + rank[i];
        csr[pos] = make_int2(src, dst);
    }
}

// ---------------- pre-splits (single launch): W[K][256] -> hi/lo [n][k] for all 4 layers ----

__global__ __launch_bounds__(256) void wsplit_all_kernel(
        const float* __restrict__ W0, const float* __restrict__ W1,
        const float* __restrict__ W2, const float* __restrict__ W3,
        _Float16* __restrict__ Th0, _Float16* __restrict__ Tl0,
        _Float16* __restrict__ Th1, _Float16* __restrict__ Tl1,
        _Float16* __restrict__ Th2, _Float16* __restrict__ Tl2,
        _Float16* __restrict__ Th3, _Float16* __restrict__ Tl3) {
    int id = blockIdx.x * 256 + threadIdx.x;
    const float* W; _Float16 *Th, *Tl; int K;
    if (id < 32768)       { W = W0; Th = Th0; Tl = Tl0; K = 128; }
    else if (id < 98304)  { W = W1; Th = Th1; Tl = Tl1; K = 256; id -= 32768; }
    else if (id < 163840) { W = W2; Th = Th2; Tl = Tl2; K = 256; id -= 98304; }
    else if (id < 229376) { W = W3; Th = Th3; Tl = Tl3; K = 256; id -= 163840; }
    else return;
    int n = id & 255, k = id >> 8;
    float w = W[(size_t)k * 256 + n];
    _Float16 h = (_Float16)w;
    _Float16 l = (_Float16)(w - (float)h);
    Th[(size_t)n * K + k] = h;
    Tl[(size_t)n * K + k] = l;
}

__global__ void xsplit_kernel(const float* __restrict__ x, _Float16* __restrict__ xh,
                              _Float16* __restrict__ xl, int total) {
    int id = blockIdx.x * 256 + threadIdx.x;
    if (id >= total) return;
    float v = x[id];
    _Float16 h = (_Float16)v;
    xh[id] = h;
    xl[id] = (_Float16)(v - (float)h);
}

// ---------------- edge-parallel softmax numerators (f16 output: exp(e) in [e^-4,e^4]) -----

__global__ __launch_bounds__(256) void edge_alpha_kernel(
        const float* __restrict__ es, const float* __restrict__ ed,
        const int2* __restrict__ csr, _Float16* __restrict__ ex) {
    int e = blockIdx.x * 256 + threadIdx.x;
    if (e >= ETOT) return;
    int2 sd = csr[e];
    float4 esv = *(const float4*)(es + (size_t)sd.x * 4);
    float4 edv = *(const float4*)(ed + (size_t)sd.y * 4);
    float4 v;
    v.x = esv.x + edv.x; v.y = esv.y + edv.y;
    v.z = esv.z + edv.z; v.w = esv.w + edv.w;
    v.x = (v.x > 0.f) ? v.x : NEG * v.x;
    v.y = (v.y > 0.f) ? v.y : NEG * v.y;
    v.z = (v.z > 0.f) ? v.z : NEG * v.z;
    v.w = (v.w > 0.f) ? v.w : NEG * v.w;
    half4v o = {(_Float16)__expf(v.x), (_Float16)__expf(v.y),
                (_Float16)__expf(v.z), (_Float16)__expf(v.w)};
    *(half4v*)(ex + (size_t)e * 4) = o;
}

// ---------------- f16 MFMA GEMM + fused es/ed epilogue ----------------
// v6 (round 9 counters: MfmaUtil==VALUBusy==11%, Occupancy 13.7% -> latency-bound
// with too few resident waves):
//  * 512 threads / 8 waves per block; wave w = (head w>>1, row-half w&1) owns a
//    32x64 output tile -> acc = 2x4 frags = 32 VGPRs (was 64). Per-wave critical
//    path halves.
//  * __launch_bounds__(512, 6) -> <=85 VGPRs -> 6 waves/SIMD -> 3 blocks/CU
//    -> 768 of 782 blocks resident in ONE block-wave (tail 1.53x -> 1.02x),
//    ~24 waves/CU for latency hiding (was ~8). Hot-loop live set ~60 VGPRs,
//    so the cap should not spill (round-5 hazard checked).
//  * B from L2 to registers (no LDS), barrier-free K loop (kept from v5).
//  * A staged once in LDS (64x(K+8), 2-way bank alias = free).

template<int K, bool HASLO>
struct SmemA {
    _Float16 Ah[64][K + 8];
    _Float16 Al[HASLO ? 64 : 1][HASLO ? (K + 8) : 8];
};
template<int K, bool HASLO>
union SmemU {
    SmemA<K, HASLO> t;
    _Float16 out[64][264];   // epilogue overlay (33792 B)
};

template<int K, bool HASLO, bool HAS2>
__global__ __launch_bounds__(512, 6) void gemm_mfma_kernel(
        const _Float16* __restrict__ A1h, const _Float16* __restrict__ A1l,
        const _Float16* __restrict__ A2h,
        const _Float16* __restrict__ Wth, const _Float16* __restrict__ Wtl,
        const float* __restrict__ a_src, const float* __restrict__ a_dst,
        _Float16* __restrict__ H16, float* __restrict__ es, float* __restrict__ ed,
        int M) {
    constexpr int CPR = K / 8;          // 16B chunks per A row
    constexpr int NC  = 64 * CPR / 512; // A chunks per thread (4 for K=256, 2 for K=128)
    __shared__ SmemU<K, HASLO> u;
    auto& Ah = u.t.Ah;
    auto& Al = u.t.Al;

    int tid = threadIdx.x;
    int m0 = blockIdx.x * 64;
    int w = tid >> 6, lane = tid & 63;
    int h  = w >> 1;          // head (output column block h*64)
    int mh = w & 1;           // row half (rows mh*32 .. mh*32+31)
    int fr = lane & 15;
    int q  = lane >> 4;
    int fk = q * 8;

    // ---- stage A (+residual / lo) into LDS once ----
    {
        half8 a1c[NC], a2c[HAS2 ? NC : 1], alc[HASLO ? NC : 1];
        #pragma unroll
        for (int c = 0; c < NC; ++c) {
            int idx = c * 512 + tid;
            int row = idx / CPR, col = (idx % CPR) * 8;
            int grow = m0 + row;
            a1c[c] = (half8)(_Float16)0;
            if (grow < M) a1c[c] = *(const half8*)(A1h + (size_t)grow * K + col);
            if constexpr (HAS2) {
                a2c[c] = (half8)(_Float16)0;
                if (grow < M) a2c[c] = *(const half8*)(A2h + (size_t)grow * K + col);
            }
            if constexpr (HASLO) {
                alc[c] = (half8)(_Float16)0;
                if (grow < M) alc[c] = *(const half8*)(A1l + (size_t)grow * K + col);
            }
        }
        #pragma unroll
        for (int c = 0; c < NC; ++c) {
            int idx = c * 512 + tid;
            int row = idx / CPR, col = (idx % CPR) * 8;
            half8 v = a1c[c];
            if constexpr (HAS2) v = v + a2c[c];
            *(half8*)&Ah[row][col] = v;
            if constexpr (HASLO) *(half8*)&Al[row][col] = alc[c];
        }
    }

    float4v acc[2][4];
    #pragma unroll
    for (int i = 0; i < 2; ++i)
        #pragma unroll
        for (int j = 0; j < 4; ++j)
            acc[i][j] = (float4v){0.f, 0.f, 0.f, 0.f};

    __syncthreads();   // A tile visible to all waves; last barrier before epilogue

    // ---- barrier-free K loop: A frags from LDS, B frags L2 -> registers ----
    const _Float16* bh_base = Wth + (size_t)(h * 64 + fr) * K + fk;
    const _Float16* bl_base = Wtl + (size_t)(h * 64 + fr) * K + fk;
    #pragma unroll 2
    for (int kk = 0; kk < K / 32; ++kk) {
        int k0 = kk * 32;
        half8 afh[2], afl[2];
        #pragma unroll
        for (int t = 0; t < 2; ++t) {
            afh[t] = *(const half8*)&Ah[mh * 32 + t * 16 + fr][k0 + fk];
            if constexpr (HASLO) afl[t] = *(const half8*)&Al[mh * 32 + t * 16 + fr][k0 + fk];
        }
        #pragma unroll
        for (int tn = 0; tn < 4; ++tn) {
            half8 bh = *(const half8*)(bh_base + (size_t)tn * 16 * K + k0);
            half8 bl = *(const half8*)(bl_base + (size_t)tn * 16 * K + k0);
            #pragma unroll
            for (int tm = 0; tm < 2; ++tm) {
                float4v c = acc[tm][tn];
                if constexpr (HASLO)
                    c = __builtin_amdgcn_mfma_f32_16x16x32_f16(afl[tm], bh, c, 0, 0, 0);
                c = __builtin_amdgcn_mfma_f32_16x16x32_f16(afh[tm], bl, c, 0, 0, 0);
                c = __builtin_amdgcn_mfma_f32_16x16x32_f16(afh[tm], bh, c, 0, 0, 0);
                acc[tm][tn] = c;
            }
        }
    }
    __syncthreads();   // all Ah/Al reads complete -> safe to overlay u.out

    // ---- epilogue part 1: es/ed (wave -> head h, rows mh*32..+31) + acc -> LDS f16 ----
    float asv[4], adv[4];
    #pragma unroll
    for (int tn = 0; tn < 4; ++tn) {
        asv[tn] = a_src[h * CHAN + tn * 16 + fr];
        adv[tn] = a_dst[h * CHAN + tn * 16 + fr];
    }
    #pragma unroll
    for (int tm = 0; tm < 2; ++tm) {
        #pragma unroll
        for (int i = 0; i < 4; ++i) {
            int r = mh * 32 + tm * 16 + q * 4 + i;
            float ps = 0.f, pd = 0.f;
            #pragma unroll
            for (int tn = 0; tn < 4; ++tn) {
                float hv = acc[tm][tn][i];
                ps += hv * asv[tn];
                pd += hv * adv[tn];
                u.out[r][h * 64 + tn * 16 + fr] = (_Float16)hv;
            }
            #pragma unroll
            for (int msk = 1; msk < 16; msk <<= 1) {
                ps += __shfl_xor(ps, msk, 64);
                pd += __shfl_xor(pd, msk, 64);
            }
            int row = m0 + r;
            if (fr == 0 && row < M) {
                es[row * NHEAD + h] = ps;
                ed[row * NHEAD + h] = pd;
            }
        }
    }
    __syncthreads();

    // ---- epilogue part 2: vectorized H16 store (16B chunks, fully coalesced) ----
    #pragma unroll
    for (int k = 0; k < 4; ++k) {
        int c = k * 512 + tid;            // 16B-chunk id within the 64x256 tile
        int r = c >> 5, cc = c & 31;
        if (m0 + r < M) {
            half8 v = *(const half8*)(&u.out[r][0] + cc * 8);
            *(half8*)(H16 + (size_t)(m0 + r) * HC + cc * 8) = v;
        }
    }
}

// ---------------- fused edge-softmax + aggregation: ONE WAVE per dst node ----------------
// Round-2 fast structure; ex is f16 (converted to f32 in the preamble).

__global__ __launch_bounds__(256) void gat_aggregate_kernel(
        const _Float16* __restrict__ H16, const _Float16* __restrict__ ex,
        const int* __restrict__ offsets, const int2* __restrict__ csr,
        const float* __restrict__ bias, _Float16* __restrict__ out16,
        float* __restrict__ out32, int do_relu) {
    __shared__ float ex_lds[4][256];
    __shared__ int   src_lds[4][64];
    int tid = threadIdx.x;
    int w = tid >> 6, lane = tid & 63;
    int n = blockIdx.x * 4 + w;
    int off = offsets[n];
    int deg = offsets[n + 1] - off;

    if (deg <= 64) {
        // --- preamble: two coalesced loads, issued concurrently ---
        int sreg = n;                           // pad lanes point at dst's own row (L1-hot)
        half4v exh = (half4v)(_Float16)0;
        if (lane < deg) {
            sreg = csr[off + lane].x;
            exh = *(const half4v*)(ex + (size_t)(off + lane) * 4);
        }
        float4 ex4 = make_float4((float)exh[0], (float)exh[1], (float)exh[2], (float)exh[3]);
        src_lds[w][lane] = sreg;
        *(float4*)&ex_lds[w][lane * 4] = ex4;   // same-wave write+read: no barrier

        // --- gather: 2 edges x 4-deep per wave; 32 lanes x 8 channels (16B loads) ---
        int hl = lane & 31, side = lane >> 5;
        int hd = hl >> 3;
        float av[8] = {0.f, 0.f, 0.f, 0.f, 0.f, 0.f, 0.f, 0.f};
        int degr = (deg + 7) & ~7;              // pad to 4 edges/side; pads have weight 0
        #pragma unroll 2
        for (int j0 = 0; j0 < degr; j0 += 8) {
            int j = j0 + side;
            int s0 = src_lds[w][j];
            int s1 = src_lds[w][j + 2];
            int s2 = src_lds[w][j + 4];
            int s3 = src_lds[w][j + 6];
            float w0 = ex_lds[w][j * 4 + hd];
            float w1 = ex_lds[w][(j + 2) * 4 + hd];
            float w2 = ex_lds[w][(j + 4) * 4 + hd];
            float w3 = ex_lds[w][(j + 6) * 4 + hd];
            half8 h0 = *(const half8*)(H16 + (size_t)s0 * HC + hl * 8);
            half8 h1 = *(const half8*)(H16 + (size_t)s1 * HC + hl * 8);
            half8 h2 = *(const half8*)(H16 + (size_t)s2 * HC + hl * 8);
            half8 h3 = *(const half8*)(H16 + (size_t)s3 * HC + hl * 8);
            #pragma unroll
            for (int c = 0; c < 8; ++c) {
                av[c] += w0 * (float)h0[c];
                av[c] += w1 * (float)h1[c];
                av[c] += w2 * (float)h2[c];
                av[c] += w3 * (float)h3[c];
            }
        }

        // --- denominators (off the gather critical path) ---
        float4 l4 = ex4;
        #pragma unroll
        for (int msk = 1; msk < 64; msk <<= 1) {
            l4.x += __shfl_xor(l4.x, msk, 64);
            l4.y += __shfl_xor(l4.y, msk, 64);
            l4.z += __shfl_xor(l4.z, msk, 64);
            l4.w += __shfl_xor(l4.w, msk, 64);
        }
        #pragma unroll
        for (int c = 0; c < 8; ++c) av[c] += __shfl_xor(av[c], 32, 64);
        if (side == 0) {
            float denom = (hd == 0) ? l4.x : (hd == 1) ? l4.y : (hd == 2) ? l4.z : l4.w;
            float scale = 1.f / (denom + 1e-16f);
            float4 b0 = *(const float4*)(bias + hl * 8);
            float4 b1 = *(const float4*)(bias + hl * 8 + 4);
            float o[8] = {av[0] * scale + b0.x, av[1] * scale + b0.y,
                          av[2] * scale + b0.z, av[3] * scale + b0.w,
                          av[4] * scale + b1.x, av[5] * scale + b1.y,
                          av[6] * scale + b1.z, av[7] * scale + b1.w};
            if (do_relu)
                #pragma unroll
                for (int c = 0; c < 8; ++c) o[c] = fmaxf(o[c], 0.f);
            if (out16) {
                half8 ov = {(_Float16)o[0], (_Float16)o[1], (_Float16)o[2], (_Float16)o[3],
                            (_Float16)o[4], (_Float16)o[5], (_Float16)o[6], (_Float16)o[7]};
                *(half8*)(out16 + (size_t)n * HC + hl * 8) = ov;
            } else {
                *(float4*)(out32 + (size_t)n * HC + hl * 8) =
                    make_float4(o[0], o[1], o[2], o[3]);
                *(float4*)(out32 + (size_t)n * HC + hl * 8 + 4) =
                    make_float4(o[4], o[5], o[6], o[7]);
            }
        }
        return;
    }

    // --- generic fallback (deg > 64): 4 channels/lane, raw-ex running sums ---
    int head = lane >> 4;
    float4 acc0 = make_float4(0.f, 0.f, 0.f, 0.f);
    float den = 0.f;
    for (int j = 0; j < deg; ++j) {
        int s = csr[off + j].x;
        float exv = (float)ex[(size_t)(off + j) * 4 + head];
        den += exv;
        half4v h0 = *(const half4v*)(H16 + (size_t)s * HC + lane * 4);
        acc0.x += exv * (float)h0[0]; acc0.y += exv * (float)h0[1];
        acc0.z += exv * (float)h0[2]; acc0.w += exv * (float)h0[3];
    }
    float scale = 1.f / (den + 1e-16f);
    float4 b4 = *(const float4*)(bias + lane * 4);
    float o[4] = {acc0.x * scale + b4.x, acc0.y * scale + b4.y,
                  acc0.z * scale + b4.z, acc0.w * scale + b4.w};
    if (do_relu)
        #pragma unroll
        for (int c = 0; c < 4; ++c) o[c] = fmaxf(o[c], 0.f);
    if (out16) {
        half4v ov = {(_Float16)o[0], (_Float16)o[1], (_Float16)o[2], (_Float16)o[3]};
        *(half4v*)(out16 + (size_t)n * HC + lane * 4) = ov;
    } else {
        *(float4*)(out32 + (size_t)n * HC + lane * 4) = make_float4(o[0], o[1], o[2], o[3]);
    }
}

// ---------------- launch ----------------

extern "C" void kernel_launch(void* const* d_in, const int* in_sizes, int n_in,
                              void* d_out, int out_size, void* d_ws, size_t ws_size,
                              hipStream_t stream) {
    const float* x  = (const float*)d_in[0];
    const int*   ei = (const int*)d_in[1];
    const float *W[5], *Asrc[5], *Adst[5], *Bs[5];
    for (int l = 0; l < 4; ++l) {
        W[l]    = (const float*)d_in[2 + l * 4];
        Asrc[l] = (const float*)d_in[3 + l * 4];
        Adst[l] = (const float*)d_in[4 + l * 4];
        Bs[l]   = (const float*)d_in[5 + l * 4];
    }
    W[4] = W[3]; Asrc[4] = Asrc[3]; Adst[4] = Adst[3]; Bs[4] = Bs[3];

    char* ws = (char*)d_ws;
    size_t off = 0;
    auto alloc = [&](size_t bytes) -> void* {
        void* p = ws + off;
        off += (bytes + 255) & ~(size_t)255;
        return p;
    };
    _Float16* h16  = (_Float16*)alloc((size_t)N_NODES * HC * 2);
    _Float16* xa   = (_Float16*)alloc((size_t)N_NODES * HC * 2);
    _Float16* xb   = (_Float16*)alloc((size_t)N_NODES * HC * 2);
    _Float16* xc   = (_Float16*)alloc((size_t)N_NODES * HC * 2);
    _Float16* xd   = (_Float16*)alloc((size_t)N_NODES * HC * 2);
    _Float16* xh   = (_Float16*)alloc((size_t)N_NODES * 128 * 2);
    _Float16* xl   = (_Float16*)alloc((size_t)N_NODES * 128 * 2);
    float* es      = (float*)alloc((size_t)N_NODES * 4 * 4);
    float* ed      = (float*)alloc((size_t)N_NODES * 4 * 4);
    _Float16* exbuf = (_Float16*)alloc((size_t)ETOT * 4 * 2);
    int*   counts  = (int*)alloc((size_t)N_NODES * 4);
    int*   offsets = (int*)alloc((size_t)(N_NODES + 1) * 4);
    int*   rank    = (int*)alloc((size_t)ETOT * 4);
    int2*  csr     = (int2*)alloc((size_t)ETOT * 8);
    int*   blocksums = (int*)alloc((size_t)NBLK * 4);
    _Float16 *Wth[5], *Wtl[5];
    int Ks[4] = {128, 256, 256, 256};
    for (int l = 0; l < 4; ++l) {
        Wth[l] = (_Float16*)alloc((size_t)256 * Ks[l] * 2);
        Wtl[l] = (_Float16*)alloc((size_t)256 * Ks[l] * 2);
    }
    Wth[4] = Wth[3]; Wtl[4] = Wtl[3];

    hipMemsetAsync(counts, 0, (size_t)N_NODES * 4, stream);
    count_rank_kernel<<<(ETOT + 1023) / 1024, 256, 0, stream>>>(ei, counts, rank);
    blocksum_kernel<<<NBLK, 256, 0, stream>>>(counts, blocksums);
    blockscan_kernel<<<1, 64, 0, stream>>>(blocksums);
    scatter_scan_kernel<<<NBLK, 1024, 0, stream>>>(counts, blocksums, offsets);
    fill_kernel<<<(ETOT + 1023) / 1024, 256, 0, stream>>>(ei, rank, offsets, csr);
    wsplit_all_kernel<<<(229376 + 255) / 256, 256, 0, stream>>>(
        W[0], W[1], W[2], W[3],
        Wth[0], Wtl[0], Wth[1], Wtl[1], Wth[2], Wtl[2], Wth[3], Wtl[3]);
    xsplit_kernel<<<(N_NODES * 128 + 255) / 256, 256, 0, stream>>>(x, xh, xl, N_NODES * 128);

    int gemm_grid = (N_NODES + 63) / 64;
    auto agg = [&](int l, _Float16* o16, float* o32, int relu) {
        edge_alpha_kernel<<<(ETOT + 255) / 256, 256, 0, stream>>>(
            es, ed, csr, exbuf);
        gat_aggregate_kernel<<<N_NODES / 4, 256, 0, stream>>>(
            h16, exbuf, offsets, csr, Bs[l], o16, o32, relu);
    };

    float* out = (float*)d_out;
    // x1 = relu(gat(x))           : K=128, A-lo, no residual
    gemm_mfma_kernel<128, true, false><<<gemm_grid, 512, 0, stream>>>(
        xh, xl, nullptr, Wth[0], Wtl[0], Asrc[0], Adst[0], h16, es, ed, N_NODES);
    agg(0, xa, nullptr, 1);
    // x2 = relu(gat(x1))          : K=256
    gemm_mfma_kernel<256, false, false><<<gemm_grid, 512, 0, stream>>>(
        xa, nullptr, nullptr, Wth[1], Wtl[1], Asrc[1], Adst[1], h16, es, ed, N_NODES);
    agg(1, xb, nullptr, 1);
    // x3 = relu(gat(x2+x1))       : K=256, residual
    gemm_mfma_kernel<256, false, true><<<gemm_grid, 512, 0, stream>>>(
        xb, nullptr, xa, Wth[2], Wtl[2], Asrc[2], Adst[2], h16, es, ed, N_NODES);
    agg(2, xc, nullptr, 1);
    // x4 = relu(gat(x2+x3))       : K=256, residual
    gemm_mfma_kernel<256, false, true><<<gemm_grid, 512, 0, stream>>>(
        xb, nullptr, xc, Wth[3], Wtl[3], Asrc[3], Adst[3], h16, es, ed, N_NODES);
    agg(3, xd, nullptr, 1);
    // x5 = gat(x4+x3), no relu    : K=256, residual (layer-4 weights again)
    gemm_mfma_kernel<256, false, true><<<gemm_grid, 512, 0, stream>>>(
        xd, nullptr, xc, Wth[4], Wtl[4], Asrc[4], Adst[4], h16, es, ed, N_NODES);
    agg(4, nullptr, out, 0);
}

// Round 12
// 717.815 us; speedup vs baseline: 1.2359x; 1.2359x over previous
//
#include <hip/hip_runtime.h>
#include <hip/hip_bf16.h>

#define N_NODES 50000
#define E_EDGES 800000
#define ETOT (E_EDGES + N_NODES)
#define HC 256
#define NHEAD 4
#define CHAN 64
#define NEG 0.2f
#define NBLK ((N_NODES + 1023) / 1024)   // 49

typedef _Float16 half8 __attribute__((ext_vector_type(8)));
typedef _Float16 half4v __attribute__((ext_vector_type(4)));
typedef float float4v __attribute__((ext_vector_type(4)));

// ---------------- CSR build (once per call; shared across all 5 layers) ----------------
// ONE atomic pass: count_rank persists the atomicAdd return value as the edge's
// rank within its dst segment; fill is a deterministic (atomic-free) scatter.

__global__ __launch_bounds__(256) void count_rank_kernel(const int* __restrict__ ei,
                                                         int* __restrict__ counts,
                                                         int* __restrict__ rank) {
    int base = blockIdx.x * 1024 + threadIdx.x;
    int dst[4];
    bool val[4];
    #pragma unroll
    for (int r = 0; r < 4; ++r) {
        int i = base + r * 256;
        val[r] = (i < ETOT);
        dst[r] = 0;
        if (val[r]) dst[r] = (i < E_EDGES) ? ei[E_EDGES + i] : (i - E_EDGES);
    }
    int rk[4];
    #pragma unroll
    for (int r = 0; r < 4; ++r)
        if (val[r]) rk[r] = atomicAdd(&counts[dst[r]], 1);
    #pragma unroll
    for (int r = 0; r < 4; ++r)
        if (val[r]) rank[base + r * 256] = rk[r];
}

__global__ __launch_bounds__(256) void blocksum_kernel(const int* __restrict__ counts,
                                                       int* __restrict__ blocksums) {
    __shared__ int s[4];
    int b = blockIdx.x, tid = threadIdx.x;
    int base = b * 1024;
    int sum = 0;
    #pragma unroll
    for (int r = 0; r < 4; ++r) {
        int idx = base + r * 256 + tid;
        sum += (idx < N_NODES) ? counts[idx] : 0;
    }
    #pragma unroll
    for (int m = 1; m < 64; m <<= 1) sum += __shfl_xor(sum, m, 64);
    if ((tid & 63) == 0) s[tid >> 6] = sum;
    __syncthreads();
    if (tid == 0) blocksums[b] = s[0] + s[1] + s[2] + s[3];
}

__global__ __launch_bounds__(64) void blockscan_kernel(int* __restrict__ blocksums) {
    int tid = threadIdx.x;
    int v = (tid < NBLK) ? blocksums[tid] : 0;
    #pragma unroll
    for (int off = 1; off < 64; off <<= 1) {
        int t = __shfl_up(v, off, 64);
        if (tid >= off) v += t;
    }
    if (tid < NBLK) blocksums[tid] = v;   // inclusive
}

__global__ __launch_bounds__(1024) void scatter_scan_kernel(const int* __restrict__ counts,
                                                            const int* __restrict__ blocksums,
                                                            int* __restrict__ offsets) {
    __shared__ int s[1024];
    int b = blockIdx.x, tid = threadIdx.x;
    int idx = b * 1024 + tid;
    int v = (idx < N_NODES) ? counts[idx] : 0;
    s[tid] = v;
    __syncthreads();
    for (int off = 1; off < 1024; off <<= 1) {
        int t = (tid >= off) ? s[tid - off] : 0;
        __syncthreads();
        s[tid] += t;
        __syncthreads();
    }
    int excl = s[tid] - v + (b > 0 ? blocksums[b - 1] : 0);
    if (idx < N_NODES) offsets[idx] = excl;
    if (idx == N_NODES - 1) offsets[N_NODES] = excl + v;
}

// atomic-free scatter: pos = offsets[dst] + rank (unique by construction).
__global__ __launch_bounds__(256) void fill_kernel(const int* __restrict__ ei,
                                                   const int* __restrict__ rank,
                                                   const int* __restrict__ offsets,
                                                   int2* __restrict__ csr) {
    int base = blockIdx.x * 1024 + threadIdx.x;
    #pragma unroll
    for (int r = 0; r < 4; ++r) {
        int i = base + r * 256;
        if (i >= ETOT) continue;
        int src, dst;
        if (i < E_EDGES) { src = ei[i]; dst = ei[E_EDGES + i]; }
        else             { src = i - E_EDGES; dst = src; }
        int pos = offsets[dst] + rank[i];
        csr[pos] = make_int2(src, dst);
    }
}

// ---------------- pre-splits (single launch): W[K][256] -> hi/lo [n][k] for all 4 layers ----

__global__ __launch_bounds__(256) void wsplit_all_kernel(
        const float* __restrict__ W0, const float* __restrict__ W1,
        const float* __restrict__ W2, const float* __restrict__ W3,
        _Float16* __restrict__ Th0, _Float16* __restrict__ Tl0,
        _Float16* __restrict__ Th1, _Float16* __restrict__ Tl1,
        _Float16* __restrict__ Th2, _Float16* __restrict__ Tl2,
        _Float16* __restrict__ Th3, _Float16* __restrict__ Tl3) {
    int id = blockIdx.x * 256 + threadIdx.x;
    const float* W; _Float16 *Th, *Tl; int K;
    if (id < 32768)       { W = W0; Th = Th0; Tl = Tl0; K = 128; }
    else if (id < 98304)  { W = W1; Th = Th1; Tl = Tl1; K = 256; id -= 32768; }
    else if (id < 163840) { W = W2; Th = Th2; Tl = Tl2; K = 256; id -= 98304; }
    else if (id < 229376) { W = W3; Th = Th3; Tl = Tl3; K = 256; id -= 163840; }
    else return;
    int n = id & 255, k = id >> 8;
    float w = W[(size_t)k * 256 + n];
    _Float16 h = (_Float16)w;
    _Float16 l = (_Float16)(w - (float)h);
    Th[(size_t)n * K + k] = h;
    Tl[(size_t)n * K + k] = l;
}

__global__ void xsplit_kernel(const float* __restrict__ x, _Float16* __restrict__ xh,
                              _Float16* __restrict__ xl, int total) {
    int id = blockIdx.x * 256 + threadIdx.x;
    if (id >= total) return;
    float v = x[id];
    _Float16 h = (_Float16)v;
    xh[id] = h;
    xl[id] = (_Float16)(v - (float)h);
}

// ---------------- edge-parallel softmax numerators (f16 output: exp(e) in [e^-4,e^4]) -----

__global__ __launch_bounds__(256) void edge_alpha_kernel(
        const float* __restrict__ es, const float* __restrict__ ed,
        const int2* __restrict__ csr, _Float16* __restrict__ ex) {
    int e = blockIdx.x * 256 + threadIdx.x;
    if (e >= ETOT) return;
    int2 sd = csr[e];
    float4 esv = *(const float4*)(es + (size_t)sd.x * 4);
    float4 edv = *(const float4*)(ed + (size_t)sd.y * 4);
    float4 v;
    v.x = esv.x + edv.x; v.y = esv.y + edv.y;
    v.z = esv.z + edv.z; v.w = esv.w + edv.w;
    v.x = (v.x > 0.f) ? v.x : NEG * v.x;
    v.y = (v.y > 0.f) ? v.y : NEG * v.y;
    v.z = (v.z > 0.f) ? v.z : NEG * v.z;
    v.w = (v.w > 0.f) ? v.w : NEG * v.w;
    half4v o = {(_Float16)__expf(v.x), (_Float16)__expf(v.y),
                (_Float16)__expf(v.z), (_Float16)__expf(v.w)};
    *(half4v*)(ex + (size_t)e * 4) = o;
}

// ---------------- f16 MFMA GEMM + fused es/ed epilogue (v4 = measured best, 41us) --------
// Round-9 configuration restored verbatim: A staged once in LDS (LDA=K+8, 2-way
// bank alias = free), B staged per-32-K-chunk in LDS with prefetch-in-registers
// across the MFMA phase, vectorized H16 epilogue through the LDS overlay.
// Rounds 10/11 proved the "improvements" (barrier-free B-from-L2, 8-wave split)
// regress: B-from-L2 is a serial L2-latency chain; the wave split starves
// register-level pipelining (VGPR 40 -> no prefetch depth).

template<int K, bool HASLO>
struct SmemLayout {
    _Float16 Ah[64][K + 8];
    _Float16 Al[HASLO ? 64 : 1][HASLO ? (K + 8) : 8];
    _Float16 Bh[256][40];
    _Float16 Bl[256][40];
};
template<int K, bool HASLO>
union SmemU {
    SmemLayout<K, HASLO> t;
    _Float16 out[64][264];   // 33792 B <= sizeof(Ah[+Al]) for K=128/256
};

template<int K, bool HASLO, bool HAS2>
__global__ __launch_bounds__(256) void gemm_mfma_kernel(
        const _Float16* __restrict__ A1h, const _Float16* __restrict__ A1l,
        const _Float16* __restrict__ A2h,
        const _Float16* __restrict__ Wth, const _Float16* __restrict__ Wtl,
        const float* __restrict__ a_src, const float* __restrict__ a_dst,
        _Float16* __restrict__ H16, float* __restrict__ es, float* __restrict__ ed,
        int M) {
    constexpr int NC  = K / 32;   // A chunks per thread (64*K/8 / 256)
    constexpr int CPR = K / 8;    // 16B chunks per A row
    __shared__ SmemU<K, HASLO> u;
    auto& Ah = u.t.Ah;
    auto& Al = u.t.Al;
    auto& Bh = u.t.Bh;
    auto& Bl = u.t.Bl;

    int tid = threadIdx.x;
    int m0 = blockIdx.x * 64;
    int w = tid >> 6, lane = tid & 63;
    int rn = w * 64;
    int fr = lane & 15;
    int q  = lane >> 4;
    int fk = q * 8;

    int wr = tid >> 2;            // 0..63 (B stage: 4 thr/row)
    int wk = (tid & 3) * 8;       // 0,8,16,24

    // ---- issue the whole A tile (+residual / lo) and the first B tile ----
    half8 a1c[NC], a2c[HAS2 ? NC : 1], alc[HASLO ? NC : 1];
    #pragma unroll
    for (int c = 0; c < NC; ++c) {
        int idx = c * 256 + tid;
        int row = idx / CPR, col = (idx % CPR) * 8;
        int grow = m0 + row;
        a1c[c] = (half8)(_Float16)0;
        if (grow < M) a1c[c] = *(const half8*)(A1h + (size_t)grow * K + col);
        if constexpr (HAS2) {
            a2c[c] = (half8)(_Float16)0;
            if (grow < M) a2c[c] = *(const half8*)(A2h + (size_t)grow * K + col);
        }
        if constexpr (HASLO) {
            alc[c] = (half8)(_Float16)0;
            if (grow < M) alc[c] = *(const half8*)(A1l + (size_t)grow * K + col);
        }
    }
    half8 pbh[4], pbl[4];
    auto loadB = [&](int k0) {
        #pragma unroll
        for (int g = 0; g < 4; ++g) {
            int r = g * 64 + wr;
            pbh[g] = *(const half8*)(Wth + (size_t)r * K + k0 + wk);
            pbl[g] = *(const half8*)(Wtl + (size_t)r * K + k0 + wk);
        }
    };
    loadB(0);

    // ---- A -> LDS (once) ----
    #pragma unroll
    for (int c = 0; c < NC; ++c) {
        int idx = c * 256 + tid;
        int row = idx / CPR, col = (idx % CPR) * 8;
        half8 v = a1c[c];
        if constexpr (HAS2) v = v + a2c[c];
        *(half8*)&Ah[row][col] = v;
        if constexpr (HASLO) *(half8*)&Al[row][col] = alc[c];
    }

    float4v acc[4][4];
    #pragma unroll
    for (int i = 0; i < 4; ++i)
        #pragma unroll
        for (int j = 0; j < 4; ++j)
            acc[i][j] = (float4v){0.f, 0.f, 0.f, 0.f};

    __syncthreads();   // A tile visible to all waves

    for (int kk = 0; kk < K / 32; ++kk) {
        int k0 = kk * 32;
        #pragma unroll
        for (int g = 0; g < 4; ++g) {
            int r = g * 64 + wr;
            *(half8*)&Bh[r][wk] = pbh[g];
            *(half8*)&Bl[r][wk] = pbl[g];
        }
        __syncthreads();
        if (kk + 1 < K / 32) loadB(k0 + 32);   // next B in flight across MFMA phase
        half8 afh[4], bfh[4], bfl[4];
        #pragma unroll
        for (int t = 0; t < 4; ++t) {
            afh[t] = *(const half8*)&Ah[t * 16 + fr][k0 + fk];
            bfh[t] = *(const half8*)&Bh[rn + t * 16 + fr][fk];
            bfl[t] = *(const half8*)&Bl[rn + t * 16 + fr][fk];
        }
        if constexpr (HASLO) {
            half8 afl[4];
            #pragma unroll
            for (int t = 0; t < 4; ++t) afl[t] = *(const half8*)&Al[t * 16 + fr][k0 + fk];
            #pragma unroll
            for (int tm = 0; tm < 4; ++tm)
                #pragma unroll
                for (int tn = 0; tn < 4; ++tn)
                    acc[tm][tn] = __builtin_amdgcn_mfma_f32_16x16x32_f16(
                        afl[tm], bfh[tn], acc[tm][tn], 0, 0, 0);
        }
        #pragma unroll
        for (int tm = 0; tm < 4; ++tm)
            #pragma unroll
            for (int tn = 0; tn < 4; ++tn) {
                float4v c = acc[tm][tn];
                c = __builtin_amdgcn_mfma_f32_16x16x32_f16(afh[tm], bfl[tn], c, 0, 0, 0);
                c = __builtin_amdgcn_mfma_f32_16x16x32_f16(afh[tm], bfh[tn], c, 0, 0, 0);
                acc[tm][tn] = c;
            }
        __syncthreads();
    }
    // final barrier of the loop: all Ah/Al/Bh/Bl reads complete -> safe to overlay u.out

    // ---- epilogue part 1: es/ed (wave w == head w) + acc -> LDS f16 ----
    float asv[4], adv[4];
    #pragma unroll
    for (int tn = 0; tn < 4; ++tn) {
        asv[tn] = a_src[w * CHAN + tn * 16 + fr];
        adv[tn] = a_dst[w * CHAN + tn * 16 + fr];
    }
    #pragma unroll
    for (int tm = 0; tm < 4; ++tm) {
        #pragma unroll
        for (int i = 0; i < 4; ++i) {
            int r = tm * 16 + q * 4 + i;
            float ps = 0.f, pd = 0.f;
            #pragma unroll
            for (int tn = 0; tn < 4; ++tn) {
                float hv = acc[tm][tn][i];
                ps += hv * asv[tn];
                pd += hv * adv[tn];
                u.out[r][rn + tn * 16 + fr] = (_Float16)hv;
            }
            #pragma unroll
            for (int msk = 1; msk < 16; msk <<= 1) {
                ps += __shfl_xor(ps, msk, 64);
                pd += __shfl_xor(pd, msk, 64);
            }
            int row = m0 + r;
            if (fr == 0 && row < M) {
                es[row * NHEAD + w] = ps;
                ed[row * NHEAD + w] = pd;
            }
        }
    }
    __syncthreads();

    // ---- epilogue part 2: vectorized H16 store (16B chunks, fully coalesced) ----
    #pragma unroll
    for (int k = 0; k < 8; ++k) {
        int c = k * 256 + tid;            // 16B-chunk id within the 64x256 tile
        int r = c >> 5, cc = c & 31;
        if (m0 + r < M) {
            half8 v = *(const half8*)(&u.out[r][0] + cc * 8);
            *(half8*)(H16 + (size_t)(m0 + r) * HC + cc * 8) = v;
        }
    }
}

// ---------------- fused edge-softmax + aggregation: ONE WAVE per dst node ----------------
// Round-2 fast structure; ex is f16 (converted to f32 in the preamble).
// Single full-grid dispatch (observability split no longer needed).

__global__ __launch_bounds__(256) void gat_aggregate_kernel(
        const _Float16* __restrict__ H16, const _Float16* __restrict__ ex,
        const int* __restrict__ offsets, const int2* __restrict__ csr,
        const float* __restrict__ bias, _Float16* __restrict__ out16,
        float* __restrict__ out32, int do_relu) {
    __shared__ float ex_lds[4][256];
    __shared__ int   src_lds[4][64];
    int tid = threadIdx.x;
    int w = tid >> 6, lane = tid & 63;
    int n = blockIdx.x * 4 + w;
    int off = offsets[n];
    int deg = offsets[n + 1] - off;

    if (deg <= 64) {
        // --- preamble: two coalesced loads, issued concurrently ---
        int sreg = n;                           // pad lanes point at dst's own row (L1-hot)
        half4v exh = (half4v)(_Float16)0;
        if (lane < deg) {
            sreg = csr[off + lane].x;
            exh = *(const half4v*)(ex + (size_t)(off + lane) * 4);
        }
        float4 ex4 = make_float4((float)exh[0], (float)exh[1], (float)exh[2], (float)exh[3]);
        src_lds[w][lane] = sreg;
        *(float4*)&ex_lds[w][lane * 4] = ex4;   // same-wave write+read: no barrier

        // --- gather: 2 edges x 4-deep per wave; 32 lanes x 8 channels (16B loads) ---
        int hl = lane & 31, side = lane >> 5;
        int hd = hl >> 3;
        float av[8] = {0.f, 0.f, 0.f, 0.f, 0.f, 0.f, 0.f, 0.f};
        int degr = (deg + 7) & ~7;              // pad to 4 edges/side; pads have weight 0
        #pragma unroll 2
        for (int j0 = 0; j0 < degr; j0 += 8) {
            int j = j0 + side;
            int s0 = src_lds[w][j];
            int s1 = src_lds[w][j + 2];
            int s2 = src_lds[w][j + 4];
            int s3 = src_lds[w][j + 6];
            float w0 = ex_lds[w][j * 4 + hd];
            float w1 = ex_lds[w][(j + 2) * 4 + hd];
            float w2 = ex_lds[w][(j + 4) * 4 + hd];
            float w3 = ex_lds[w][(j + 6) * 4 + hd];
            half8 h0 = *(const half8*)(H16 + (size_t)s0 * HC + hl * 8);
            half8 h1 = *(const half8*)(H16 + (size_t)s1 * HC + hl * 8);
            half8 h2 = *(const half8*)(H16 + (size_t)s2 * HC + hl * 8);
            half8 h3 = *(const half8*)(H16 + (size_t)s3 * HC + hl * 8);
            #pragma unroll
            for (int c = 0; c < 8; ++c) {
                av[c] += w0 * (float)h0[c];
                av[c] += w1 * (float)h1[c];
                av[c] += w2 * (float)h2[c];
                av[c] += w3 * (float)h3[c];
            }
        }

        // --- denominators (off the gather critical path) ---
        float4 l4 = ex4;
        #pragma unroll
        for (int msk = 1; msk < 64; msk <<= 1) {
            l4.x += __shfl_xor(l4.x, msk, 64);
            l4.y += __shfl_xor(l4.y, msk, 64);
            l4.z += __shfl_xor(l4.z, msk, 64);
            l4.w += __shfl_xor(l4.w, msk, 64);
        }
        #pragma unroll
        for (int c = 0; c < 8; ++c) av[c] += __shfl_xor(av[c], 32, 64);
        if (side == 0) {
            float denom = (hd == 0) ? l4.x : (hd == 1) ? l4.y : (hd == 2) ? l4.z : l4.w;
            float scale = 1.f / (denom + 1e-16f);
            float4 b0 = *(const float4*)(bias + hl * 8);
            float4 b1 = *(const float4*)(bias + hl * 8 + 4);
            float o[8] = {av[0] * scale + b0.x, av[1] * scale + b0.y,
                          av[2] * scale + b0.z, av[3] * scale + b0.w,
                          av[4] * scale + b1.x, av[5] * scale + b1.y,
                          av[6] * scale + b1.z, av[7] * scale + b1.w};
            if (do_relu)
                #pragma unroll
                for (int c = 0; c < 8; ++c) o[c] = fmaxf(o[c], 0.f);
            if (out16) {
                half8 ov = {(_Float16)o[0], (_Float16)o[1], (_Float16)o[2], (_Float16)o[3],
                            (_Float16)o[4], (_Float16)o[5], (_Float16)o[6], (_Float16)o[7]};
                *(half8*)(out16 + (size_t)n * HC + hl * 8) = ov;
            } else {
                *(float4*)(out32 + (size_t)n * HC + hl * 8) =
                    make_float4(o[0], o[1], o[2], o[3]);
                *(float4*)(out32 + (size_t)n * HC + hl * 8 + 4) =
                    make_float4(o[4], o[5], o[6], o[7]);
            }
        }
        return;
    }

    // --- generic fallback (deg > 64): 4 channels/lane, raw-ex running sums ---
    int head = lane >> 4;
    float4 acc0 = make_float4(0.f, 0.f, 0.f, 0.f);
    float den = 0.f;
    for (int j = 0; j < deg; ++j) {
        int s = csr[off + j].x;
        float exv = (float)ex[(size_t)(off + j) * 4 + head];
        den += exv;
        half4v h0 = *(const half4v*)(H16 + (size_t)s * HC + lane * 4);
        acc0.x += exv * (float)h0[0]; acc0.y += exv * (float)h0[1];
        acc0.z += exv * (float)h0[2]; acc0.w += exv * (float)h0[3];
    }
    float scale = 1.f / (den + 1e-16f);
    float4 b4 = *(const float4*)(bias + lane * 4);
    float o[4] = {acc0.x * scale + b4.x, acc0.y * scale + b4.y,
                  acc0.z * scale + b4.z, acc0.w * scale + b4.w};
    if (do_relu)
        #pragma unroll
        for (int c = 0; c < 4; ++c) o[c] = fmaxf(o[c], 0.f);
    if (out16) {
        half4v ov = {(_Float16)o[0], (_Float16)o[1], (_Float16)o[2], (_Float16)o[3]};
        *(half4v*)(out16 + (size_t)n * HC + lane * 4) = ov;
    } else {
        *(float4*)(out32 + (size_t)n * HC + lane * 4) = make_float4(o[0], o[1], o[2], o[3]);
    }
}

// ---------------- launch ----------------

extern "C" void kernel_launch(void* const* d_in, const int* in_sizes, int n_in,
                              void* d_out, int out_size, void* d_ws, size_t ws_size,
                              hipStream_t stream) {
    const float* x  = (const float*)d_in[0];
    const int*   ei = (const int*)d_in[1];
    const float *W[5], *Asrc[5], *Adst[5], *Bs[5];
    for (int l = 0; l < 4; ++l) {
        W[l]    = (const float*)d_in[2 + l * 4];
        Asrc[l] = (const float*)d_in[3 + l * 4];
        Adst[l] = (const float*)d_in[4 + l * 4];
        Bs[l]   = (const float*)d_in[5 + l * 4];
    }
    W[4] = W[3]; Asrc[4] = Asrc[3]; Adst[4] = Adst[3]; Bs[4] = Bs[3];

    char* ws = (char*)d_ws;
    size_t off = 0;
    auto alloc = [&](size_t bytes) -> void* {
        void* p = ws + off;
        off += (bytes + 255) & ~(size_t)255;
        return p;
    };
    _Float16* h16  = (_Float16*)alloc((size_t)N_NODES * HC * 2);
    _Float16* xa   = (_Float16*)alloc((size_t)N_NODES * HC * 2);
    _Float16* xb   = (_Float16*)alloc((size_t)N_NODES * HC * 2);
    _Float16* xc   = (_Float16*)alloc((size_t)N_NODES * HC * 2);
    _Float16* xd   = (_Float16*)alloc((size_t)N_NODES * HC * 2);
    _Float16* xh   = (_Float16*)alloc((size_t)N_NODES * 128 * 2);
    _Float16* xl   = (_Float16*)alloc((size_t)N_NODES * 128 * 2);
    float* es      = (float*)alloc((size_t)N_NODES * 4 * 4);
    float* ed      = (float*)alloc((size_t)N_NODES * 4 * 4);
    _Float16* exbuf = (_Float16*)alloc((size_t)ETOT * 4 * 2);
    int*   counts  = (int*)alloc((size_t)N_NODES * 4);
    int*   offsets = (int*)alloc((size_t)(N_NODES + 1) * 4);
    int*   rank    = (int*)alloc((size_t)ETOT * 4);
    int2*  csr     = (int2*)alloc((size_t)ETOT * 8);
    int*   blocksums = (int*)alloc((size_t)NBLK * 4);
    _Float16 *Wth[5], *Wtl[5];
    int Ks[4] = {128, 256, 256, 256};
    for (int l = 0; l < 4; ++l) {
        Wth[l] = (_Float16*)alloc((size_t)256 * Ks[l] * 2);
        Wtl[l] = (_Float16*)alloc((size_t)256 * Ks[l] * 2);
    }
    Wth[4] = Wth[3]; Wtl[4] = Wtl[3];

    hipMemsetAsync(counts, 0, (size_t)N_NODES * 4, stream);
    count_rank_kernel<<<(ETOT + 1023) / 1024, 256, 0, stream>>>(ei, counts, rank);
    blocksum_kernel<<<NBLK, 256, 0, stream>>>(counts, blocksums);
    blockscan_kernel<<<1, 64, 0, stream>>>(blocksums);
    scatter_scan_kernel<<<NBLK, 1024, 0, stream>>>(counts, blocksums, offsets);
    fill_kernel<<<(ETOT + 1023) / 1024, 256, 0, stream>>>(ei, rank, offsets, csr);
    wsplit_all_kernel<<<(229376 + 255) / 256, 256, 0, stream>>>(
        W[0], W[1], W[2], W[3],
        Wth[0], Wtl[0], Wth[1], Wtl[1], Wth[2], Wtl[2], Wth[3], Wtl[3]);
    xsplit_kernel<<<(N_NODES * 128 + 255) / 256, 256, 0, stream>>>(x, xh, xl, N_NODES * 128);

    int gemm_grid = (N_NODES + 63) / 64;
    auto agg = [&](int l, _Float16* o16, float* o32, int relu) {
        edge_alpha_kernel<<<(ETOT + 255) / 256, 256, 0, stream>>>(
            es, ed, csr, exbuf);
        gat_aggregate_kernel<<<N_NODES / 4, 256, 0, stream>>>(
            h16, exbuf, offsets, csr, Bs[l], o16, o32, relu);
    };

    float* out = (float*)d_out;
    // x1 = relu(gat(x))           : K=128, A-lo, no residual
    gemm_mfma_kernel<128, true, false><<<gemm_grid, 256, 0, stream>>>(
        xh, xl, nullptr, Wth[0], Wtl[0], Asrc[0], Adst[0], h16, es, ed, N_NODES);
    agg(0, xa, nullptr, 1);
    // x2 = relu(gat(x1))          : K=256
    gemm_mfma_kernel<256, false, false><<<gemm_grid, 256, 0, stream>>>(
        xa, nullptr, nullptr, Wth[1], Wtl[1], Asrc[1], Adst[1], h16, es, ed, N_NODES);
    agg(1, xb, nullptr, 1);
    // x3 = relu(gat(x2+x1))       : K=256, residual
    gemm_mfma_kernel<256, false, true><<<gemm_grid, 256, 0, stream>>>(
        xb, nullptr, xa, Wth[2], Wtl[2], Asrc[2], Adst[2], h16, es, ed, N_NODES);
    agg(2, xc, nullptr, 1);
    // x4 = relu(gat(x2+x3))       : K=256, residual
    gemm_mfma_kernel<256, false, true><<<gemm_grid, 256, 0, stream>>>(
        xb, nullptr, xc, Wth[3], Wtl[3], Asrc[3], Adst[3], h16, es, ed, N_NODES);
    agg(3, xd, nullptr, 1);
    // x5 = gat(x4+x3), no relu    : K=256, residual (layer-4 weights again)
    gemm_mfma_kernel<256, false, true><<<gemm_grid, 256, 0, stream>>>(
        xd, nullptr, xc, Wth[4], Wtl[4], Asrc[4], Adst[4], h16, es, ed, N_NODES);
    agg(4, nullptr, out, 0);
}